// Round 8
// baseline (588.029 us; speedup 1.0000x reference)
//
#include <hip/hip_runtime.h>
#include <hip/hip_fp16.h>

#define BB 512
#define NN 256
#define SS 128
#define MM 64
#define UNFOLDS 6

static constexpr float EPS_ = 1e-8f;
static constexpr float L2E = 1.4426950408889634f;

// Packed param layout: float4 per pair of i-entries:
//   {bitcast(half2{a_i, c_i}), wE_i, bitcast(half2{a_i1, c_i1}), wE_i1}
// gate = 1/(1+exp2(a*v + c)); a = -sigma*log2e; c = sigma*mu*log2e
__global__ __launch_bounds__(256) void prep_pack(
    const float* __restrict__ w, const float* __restrict__ sg,
    const float* __restrict__ mu, const float* __restrict__ E,
    const float* __restrict__ mask,
    const float* __restrict__ sw, const float* __restrict__ ssg,
    const float* __restrict__ smu, const float* __restrict__ sE,
    const float* __restrict__ smask,
    const float* __restrict__ iw, const float* __restrict__ ib,
    float4* __restrict__ PQ, float4* __restrict__ SQ) {
  int idx = blockIdx.x * 256 + threadIdx.x;
  union { __half2 h; float f; } u_;
  if (idx < NN * NN) {
    int i = idx >> 8, j = idx & 255;
    float a = sg[idx] * L2E;
    u_.h = __floats2half2_rn(-a, a * mu[idx]);
    float wE = w[idx] * mask[idx] * E[idx];
    float* dst = (float*)(PQ + (i >> 1) * NN + j);
    dst[(i & 1) * 2 + 0] = u_.f;
    dst[(i & 1) * 2 + 1] = wE;
  } else {
    int e = idx - NN * NN;        // < SS*NN
    int s = e >> 8, j = e & 255;
    float a = ssg[e] * L2E;
    // fold input affine: a' = -a*iw[s], c' = a*(smu - ib[s])
    u_.h = __floats2half2_rn(-a * iw[s], a * (smu[e] - ib[s]));
    float wE = sw[e] * smask[e] * sE[e];
    float* dst = (float*)(SQ + (s >> 1) * NN + j);
    dst[(s & 1) * 2 + 0] = u_.f;
    dst[(s & 1) * 2 + 1] = wE;
  }
}

// 4 gates (2 param entries x 2 batches) from one float4 param + one float4 of v
#define GATE4(pq, vv) do { \
  union { float f; __half2 h; } _u0, _u1; \
  _u0.f = (pq).x; _u1.f = (pq).z; \
  float2 ac0 = __half22float2(_u0.h); \
  float2 ac1 = __half22float2(_u1.h); \
  float g0a = __builtin_amdgcn_rcpf(1.f + __builtin_amdgcn_exp2f(fmaf(ac0.x, (vv).x, ac0.y))); \
  float g0b = __builtin_amdgcn_rcpf(1.f + __builtin_amdgcn_exp2f(fmaf(ac0.x, (vv).y, ac0.y))); \
  float g1a = __builtin_amdgcn_rcpf(1.f + __builtin_amdgcn_exp2f(fmaf(ac1.x, (vv).z, ac1.y))); \
  float g1b = __builtin_amdgcn_rcpf(1.f + __builtin_amdgcn_exp2f(fmaf(ac1.x, (vv).w, ac1.y))); \
  n0 = fmaf((pq).y, g0a, n0); d0 = fmaf(__builtin_fabsf((pq).y), g0a, d0); \
  n1 = fmaf((pq).y, g0b, n1); d1 = fmaf(__builtin_fabsf((pq).y), g0b, d1); \
  n0 = fmaf((pq).w, g1a, n0); d0 = fmaf(__builtin_fabsf((pq).w), g1a, d0); \
  n1 = fmaf((pq).w, g1b, n1); d1 = fmaf(__builtin_fabsf((pq).w), g1b, d1); \
} while (0)

// one block = 2 batches x all 256 columns, all unfolds; no cross-block deps.
// 1024 threads: j = tid&255 (column), split = tid>>8 (4-way over i).
// Inner loop: register double-buffered global prefetch (depth 8) + batched
// ds_read_b128 v loads. VGPR audit: pb 64 + vb 32 + misc ~20 < 128 (no spill).
__global__ __launch_bounds__(1024) void ltc_dense(
    const float* __restrict__ x, const float* __restrict__ state,
    const float* __restrict__ gl, const float* __restrict__ rp,
    const float* __restrict__ cap,
    const float* __restrict__ ow, const float* __restrict__ ob,
    const float4* __restrict__ PQ, const float4* __restrict__ SQ,
    float* __restrict__ out) {
  __shared__ float4 vA[NN / 2], vB[NN / 2];   // v[i-pair]{b0,b1,b0,b1}, 2 KiB each
  __shared__ float4 xt[SS / 2];               // 1 KiB
  __shared__ float4 snd[NN];                  // {n0,n1,d0,d1} per column, 4 KiB
  __shared__ float4 red[3][NN];               // partials, 12 KiB
  int tid = threadIdx.x;
  int j = tid & 255;
  int split = tid >> 8;
  int bbase = blockIdx.x * 2;

  if (tid < 512) {
    int b = tid >> 8, i = tid & 255;
    ((float*)vA)[(i >> 1) * 4 + (i & 1) * 2 + b] = state[(bbase + b) * NN + i];
  } else if (tid < 768) {
    int t = tid - 512, b = t >> 7, s = t & 127;
    ((float*)xt)[(s >> 1) * 4 + (s & 1) * 2 + b] = x[(bbase + b) * SS + s];
  }
  __syncthreads();

  // ---- sensory aggregation (16 chunks per split, dbuf depth 8) ----
  {
    float n0 = 0, n1 = 0, d0 = 0, d1 = 0;
    const float4* Sp = SQ + split * 16 * NN + j;
    const float4* xq = xt + split * 16;
    float4 pb[2][8], vb[8];
#pragma unroll
    for (int k = 0; k < 8; ++k) pb[0][k] = Sp[k * NN];
#pragma unroll
    for (int g = 0; g < 2; ++g) {
      if (g < 1) {
#pragma unroll
        for (int k = 0; k < 8; ++k) pb[(g + 1) & 1][k] = Sp[((g + 1) * 8 + k) * NN];
      }
#pragma unroll
      for (int k = 0; k < 8; ++k) vb[k] = xq[g * 8 + k];
#pragma unroll
      for (int k = 0; k < 8; ++k) { float4 pq = pb[g & 1][k]; float4 vv = vb[k]; GATE4(pq, vv); }
    }
    if (split) red[split - 1][j] = make_float4(n0, n1, d0, d1);
    __syncthreads();
    if (split == 0) {
      float4 r0 = red[0][j], r1 = red[1][j], r2 = red[2][j];
      snd[j] = make_float4(n0 + r0.x + r1.x + r2.x, n1 + r0.y + r1.y + r2.y,
                           d0 + r0.z + r1.z + r2.z, d1 + r0.w + r1.w + r2.w);
    }
    __syncthreads();
  }

  float cmt = cap[j] * (float)UNFOLDS;
  float glv = gl[j];
  float base_ = glv * rp[j];

  // ---- 6 unfolds, v ping-pongs in LDS ----
  for (int u = 0; u < UNFOLDS; ++u) {
    const float4* vcur = (u & 1) ? vB : vA;
    float4* vnext = (u & 1) ? vA : vB;
    float n0 = 0, n1 = 0, d0 = 0, d1 = 0;
    const float4* Pp = PQ + split * 32 * NN + j;
    const float4* vq = vcur + split * 32;
    float4 pb[2][8], vb[8];
#pragma unroll
    for (int k = 0; k < 8; ++k) pb[0][k] = Pp[k * NN];
#pragma unroll
    for (int g = 0; g < 4; ++g) {
      if (g < 3) {
#pragma unroll
        for (int k = 0; k < 8; ++k) pb[(g + 1) & 1][k] = Pp[((g + 1) * 8 + k) * NN];
      }
#pragma unroll
      for (int k = 0; k < 8; ++k) vb[k] = vq[g * 8 + k];
#pragma unroll
      for (int k = 0; k < 8; ++k) { float4 pq = pb[g & 1][k]; float4 vv = vb[k]; GATE4(pq, vv); }
    }
    if (split) red[split - 1][j] = make_float4(n0, n1, d0, d1);
    __syncthreads();
    if (split == 0) {
      float4 r0 = red[0][j], r1 = red[1][j], r2 = red[2][j], sj = snd[j];
      float N0 = n0 + r0.x + r1.x + r2.x + sj.x;
      float N1 = n1 + r0.y + r1.y + r2.y + sj.y;
      float D0 = d0 + r0.z + r1.z + r2.z + sj.z;
      float D1 = d1 + r0.w + r1.w + r2.w + sj.w;
      const float* vcf = (const float*)vcur;
      float vj0 = vcf[(j >> 1) * 4 + (j & 1) * 2 + 0];
      float vj1 = vcf[(j >> 1) * 4 + (j & 1) * 2 + 1];
      float va = (fmaf(cmt, vj0, base_) + N0) * __builtin_amdgcn_rcpf(cmt + glv + D0 + EPS_);
      float vb2 = (fmaf(cmt, vj1, base_) + N1) * __builtin_amdgcn_rcpf(cmt + glv + D1 + EPS_);
      float* vnf = (float*)vnext;
      vnf[(j >> 1) * 4 + (j & 1) * 2 + 0] = va;
      vnf[(j >> 1) * 4 + (j & 1) * 2 + 1] = vb2;
      if (u == UNFOLDS - 1) {
        out[BB * MM + (bbase + 0) * NN + j] = va;
        out[BB * MM + (bbase + 1) * NN + j] = vb2;
        if (j < MM) {
          out[(bbase + 0) * MM + j] = fmaf(va, ow[j], ob[j]);
          out[(bbase + 1) * MM + j] = fmaf(vb2, ow[j], ob[j]);
        }
      }
    }
    __syncthreads();
  }
}

extern "C" void kernel_launch(void* const* d_in, const int* in_sizes, int n_in,
                              void* d_out, int out_size, void* d_ws, size_t ws_size,
                              hipStream_t stream) {
  const float* x     = (const float*)d_in[0];
  const float* state = (const float*)d_in[1];
  const float* gl    = (const float*)d_in[2];
  const float* rp    = (const float*)d_in[3];
  const float* cap   = (const float*)d_in[4];
  const float* w     = (const float*)d_in[5];
  const float* sg    = (const float*)d_in[6];
  const float* mu    = (const float*)d_in[7];
  const float* E     = (const float*)d_in[8];
  const float* sw    = (const float*)d_in[9];
  const float* ssg   = (const float*)d_in[10];
  const float* smu   = (const float*)d_in[11];
  const float* sE    = (const float*)d_in[12];
  const float* mask  = (const float*)d_in[13];
  const float* smask = (const float*)d_in[14];
  const float* iw    = (const float*)d_in[15];
  const float* ib    = (const float*)d_in[16];
  const float* ow    = (const float*)d_in[17];
  const float* ob    = (const float*)d_in[18];

  float4* PQ = (float4*)d_ws;                  // [NN/2][NN] = 512 KiB
  float4* SQ = PQ + (NN / 2) * NN;             // [SS/2][NN] = 256 KiB
  float* fout = (float*)d_out;                 // [B*M out][B*N v]

  prep_pack<<<(NN * NN + SS * NN) / 256, 256, 0, stream>>>(
      w, sg, mu, E, mask, sw, ssg, smu, sE, smask, iw, ib, PQ, SQ);
  ltc_dense<<<BB / 2, 1024, 0, stream>>>(
      x, state, gl, rp, cap, ow, ob, PQ, SQ, fout);
}

// Round 9
// 581.109 us; speedup vs baseline: 1.0119x; 1.0119x over previous
//
#include <hip/hip_runtime.h>
#include <hip/hip_fp16.h>

#define BB 512
#define NN 256
#define SS 128
#define MM 64
#define UNFOLDS 6

static constexpr float EPS_ = 1e-8f;
static constexpr float L2E = 1.4426950408889634f;

// fp16 packed params, 6 B/entry, grouped by 4 consecutive i per column j:
//   PA[i4*NN+j] = float4 bitcast of 4x half2 {a_i, c_i},  i = 4*i4..4*i4+3
//   PW[i4*NN+j] = uint2  bitcast of 4x half  wE_i
// gate = 1/(1+exp2(a*v + c)); a = -sigma*log2e; c = sigma*mu*log2e
__global__ __launch_bounds__(256) void prep_pack(
    const float* __restrict__ w, const float* __restrict__ sg,
    const float* __restrict__ mu, const float* __restrict__ E,
    const float* __restrict__ mask,
    const float* __restrict__ sw, const float* __restrict__ ssg,
    const float* __restrict__ smu, const float* __restrict__ sE,
    const float* __restrict__ smask,
    const float* __restrict__ iw, const float* __restrict__ ib,
    float4* __restrict__ PA, uint2* __restrict__ PW,
    float4* __restrict__ SA, uint2* __restrict__ SW) {
  int idx = blockIdx.x * 256 + threadIdx.x;
  if (idx < NN * NN) {
    int i = idx >> 8, j = idx & 255;
    float a = sg[idx] * L2E;
    __half2 h = __floats2half2_rn(-a, a * mu[idx]);
    float wE = w[idx] * mask[idx] * E[idx];
    ((__half2*)PA)[((i >> 2) * NN + j) * 4 + (i & 3)] = h;
    ((__half*)PW)[((i >> 2) * NN + j) * 4 + (i & 3)] = __float2half_rn(wE);
  } else {
    int e = idx - NN * NN;        // < SS*NN
    int s = e >> 8, j = e & 255;
    float a = ssg[e] * L2E;
    // fold input affine: a' = -a*iw[s], c' = a*(smu - ib[s])
    __half2 h = __floats2half2_rn(-a * iw[s], a * (smu[e] - ib[s]));
    float wE = sw[e] * smask[e] * sE[e];
    ((__half2*)SA)[((s >> 2) * NN + j) * 4 + (s & 3)] = h;
    ((__half*)SW)[((s >> 2) * NN + j) * 4 + (s & 3)] = __float2half_rn(wE);
  }
}

// 8 gates (4 i-entries x 2 batches) from one float4 ac-pack + one uint2 wE-pack
// + two float4 of v (layout {v(2p)b0, v(2p)b1, v(2p+1)b0, v(2p+1)b1}).
#define GATE8(pa, pw, v01, v23) do { \
  union { float f; __half2 h; } _a0, _a1, _a2, _a3; \
  _a0.f = (pa).x; _a1.f = (pa).y; _a2.f = (pa).z; _a3.f = (pa).w; \
  float2 ac0 = __half22float2(_a0.h), ac1 = __half22float2(_a1.h); \
  float2 ac2 = __half22float2(_a2.h), ac3 = __half22float2(_a3.h); \
  union { unsigned u; __half2 h; } _w01, _w23; \
  _w01.u = (pw).x; _w23.u = (pw).y; \
  float2 wf01 = __half22float2(_w01.h), wf23 = __half22float2(_w23.h); \
  float g0a = __builtin_amdgcn_rcpf(1.f + __builtin_amdgcn_exp2f(fmaf(ac0.x, (v01).x, ac0.y))); \
  float g0b = __builtin_amdgcn_rcpf(1.f + __builtin_amdgcn_exp2f(fmaf(ac0.x, (v01).y, ac0.y))); \
  float g1a = __builtin_amdgcn_rcpf(1.f + __builtin_amdgcn_exp2f(fmaf(ac1.x, (v01).z, ac1.y))); \
  float g1b = __builtin_amdgcn_rcpf(1.f + __builtin_amdgcn_exp2f(fmaf(ac1.x, (v01).w, ac1.y))); \
  float g2a = __builtin_amdgcn_rcpf(1.f + __builtin_amdgcn_exp2f(fmaf(ac2.x, (v23).x, ac2.y))); \
  float g2b = __builtin_amdgcn_rcpf(1.f + __builtin_amdgcn_exp2f(fmaf(ac2.x, (v23).y, ac2.y))); \
  float g3a = __builtin_amdgcn_rcpf(1.f + __builtin_amdgcn_exp2f(fmaf(ac3.x, (v23).z, ac3.y))); \
  float g3b = __builtin_amdgcn_rcpf(1.f + __builtin_amdgcn_exp2f(fmaf(ac3.x, (v23).w, ac3.y))); \
  n0 = fmaf(wf01.x, g0a, n0); d0 = fmaf(__builtin_fabsf(wf01.x), g0a, d0); \
  n1 = fmaf(wf01.x, g0b, n1); d1 = fmaf(__builtin_fabsf(wf01.x), g0b, d1); \
  n0 = fmaf(wf01.y, g1a, n0); d0 = fmaf(__builtin_fabsf(wf01.y), g1a, d0); \
  n1 = fmaf(wf01.y, g1b, n1); d1 = fmaf(__builtin_fabsf(wf01.y), g1b, d1); \
  n0 = fmaf(wf23.x, g2a, n0); d0 = fmaf(__builtin_fabsf(wf23.x), g2a, d0); \
  n1 = fmaf(wf23.x, g2b, n1); d1 = fmaf(__builtin_fabsf(wf23.x), g2b, d1); \
  n0 = fmaf(wf23.y, g3a, n0); d0 = fmaf(__builtin_fabsf(wf23.y), g3a, d0); \
  n1 = fmaf(wf23.y, g3b, n1); d1 = fmaf(__builtin_fabsf(wf23.y), g3b, d1); \
} while (0)

// one block = 2 batches x all 256 columns, all unfolds; no cross-block deps.
// 1024 threads: j = tid&255 (column), split = tid>>8 (4-way over i).
// Loads consumed immediately (no register arrays) -> no spill (R7/R8 lesson).
__global__ __launch_bounds__(1024, 4) void ltc_dense(
    const float* __restrict__ x, const float* __restrict__ state,
    const float* __restrict__ gl, const float* __restrict__ rp,
    const float* __restrict__ cap,
    const float* __restrict__ ow, const float* __restrict__ ob,
    const float4* __restrict__ PA, const uint2* __restrict__ PW,
    const float4* __restrict__ SA, const uint2* __restrict__ SW,
    float* __restrict__ out) {
  __shared__ float4 vA[NN / 2], vB[NN / 2];   // v[i-pair]{b0,b1,b0,b1}, 2 KiB each
  __shared__ float4 xt[SS / 2];               // 1 KiB
  __shared__ float4 snd[NN];                  // {n0,n1,d0,d1} per column, 4 KiB
  __shared__ float4 red[3][NN];               // partials, 12 KiB
  int tid = threadIdx.x;
  int j = tid & 255;
  int split = tid >> 8;
  int bbase = blockIdx.x * 2;

  if (tid < 512) {
    int b = tid >> 8, i = tid & 255;
    ((float*)vA)[(i >> 1) * 4 + (i & 1) * 2 + b] = state[(bbase + b) * NN + i];
  } else if (tid < 768) {
    int t = tid - 512, b = t >> 7, s = t & 127;
    ((float*)xt)[(s >> 1) * 4 + (s & 1) * 2 + b] = x[(bbase + b) * SS + s];
  }
  __syncthreads();

  // ---- sensory aggregation: 8 chunks of 4 s-entries per split ----
  {
    float n0 = 0, n1 = 0, d0 = 0, d1 = 0;
    const float4* Sa = SA + split * 8 * NN + j;
    const uint2*  Sw = SW + split * 8 * NN + j;
    const float4* xq = xt + split * 16;
#pragma unroll
    for (int c = 0; c < 8; ++c) {
      float4 pa = Sa[c * NN];
      uint2  pw = Sw[c * NN];
      float4 v01 = xq[2 * c], v23 = xq[2 * c + 1];
      GATE8(pa, pw, v01, v23);
    }
    if (split) red[split - 1][j] = make_float4(n0, n1, d0, d1);
    __syncthreads();
    if (split == 0) {
      float4 r0 = red[0][j], r1 = red[1][j], r2 = red[2][j];
      snd[j] = make_float4(n0 + r0.x + r1.x + r2.x, n1 + r0.y + r1.y + r2.y,
                           d0 + r0.z + r1.z + r2.z, d1 + r0.w + r1.w + r2.w);
    }
    __syncthreads();
  }

  float cmt = cap[j] * (float)UNFOLDS;
  float glv = gl[j];
  float base_ = glv * rp[j];

  // ---- 6 unfolds, v ping-pongs in LDS ----
  for (int u = 0; u < UNFOLDS; ++u) {
    const float4* vcur = (u & 1) ? vB : vA;
    float4* vnext = (u & 1) ? vA : vB;
    float n0 = 0, n1 = 0, d0 = 0, d1 = 0;
    const float4* Pa = PA + split * 16 * NN + j;
    const uint2*  Pw = PW + split * 16 * NN + j;
    const float4* vq = vcur + split * 32;
#pragma unroll
    for (int c = 0; c < 16; ++c) {
      float4 pa = Pa[c * NN];
      uint2  pw = Pw[c * NN];
      float4 v01 = vq[2 * c], v23 = vq[2 * c + 1];
      GATE8(pa, pw, v01, v23);
    }
    if (split) red[split - 1][j] = make_float4(n0, n1, d0, d1);
    __syncthreads();
    if (split == 0) {
      float4 r0 = red[0][j], r1 = red[1][j], r2 = red[2][j], sj = snd[j];
      float N0 = n0 + r0.x + r1.x + r2.x + sj.x;
      float N1 = n1 + r0.y + r1.y + r2.y + sj.y;
      float D0 = d0 + r0.z + r1.z + r2.z + sj.z;
      float D1 = d1 + r0.w + r1.w + r2.w + sj.w;
      const float* vcf = (const float*)vcur;
      float vj0 = vcf[(j >> 1) * 4 + (j & 1) * 2 + 0];
      float vj1 = vcf[(j >> 1) * 4 + (j & 1) * 2 + 1];
      float va = (fmaf(cmt, vj0, base_) + N0) * __builtin_amdgcn_rcpf(cmt + glv + D0 + EPS_);
      float vb2 = (fmaf(cmt, vj1, base_) + N1) * __builtin_amdgcn_rcpf(cmt + glv + D1 + EPS_);
      float* vnf = (float*)vnext;
      vnf[(j >> 1) * 4 + (j & 1) * 2 + 0] = va;
      vnf[(j >> 1) * 4 + (j & 1) * 2 + 1] = vb2;
      if (u == UNFOLDS - 1) {
        out[BB * MM + (bbase + 0) * NN + j] = va;
        out[BB * MM + (bbase + 1) * NN + j] = vb2;
        if (j < MM) {
          out[(bbase + 0) * MM + j] = fmaf(va, ow[j], ob[j]);
          out[(bbase + 1) * MM + j] = fmaf(vb2, ow[j], ob[j]);
        }
      }
    }
    __syncthreads();
  }
}

extern "C" void kernel_launch(void* const* d_in, const int* in_sizes, int n_in,
                              void* d_out, int out_size, void* d_ws, size_t ws_size,
                              hipStream_t stream) {
  const float* x     = (const float*)d_in[0];
  const float* state = (const float*)d_in[1];
  const float* gl    = (const float*)d_in[2];
  const float* rp    = (const float*)d_in[3];
  const float* cap   = (const float*)d_in[4];
  const float* w     = (const float*)d_in[5];
  const float* sg    = (const float*)d_in[6];
  const float* mu    = (const float*)d_in[7];
  const float* E     = (const float*)d_in[8];
  const float* sw    = (const float*)d_in[9];
  const float* ssg   = (const float*)d_in[10];
  const float* smu   = (const float*)d_in[11];
  const float* sE    = (const float*)d_in[12];
  const float* mask  = (const float*)d_in[13];
  const float* smask = (const float*)d_in[14];
  const float* iw    = (const float*)d_in[15];
  const float* ib    = (const float*)d_in[16];
  const float* ow    = (const float*)d_in[17];
  const float* ob    = (const float*)d_in[18];

  float4* PA = (float4*)d_ws;                       // (NN/4)*NN*16 = 256 KiB
  uint2*  PW = (uint2*)(PA + (NN / 4) * NN);        // (NN/4)*NN*8  = 128 KiB
  float4* SA = (float4*)(PW + (NN / 4) * NN);       // (SS/4)*NN*16 = 128 KiB
  uint2*  SW = (uint2*)(SA + (SS / 4) * NN);        // (SS/4)*NN*8  =  64 KiB
  float* fout = (float*)d_out;                      // [B*M out][B*N v]

  prep_pack<<<(NN * NN + SS * NN) / 256, 256, 0, stream>>>(
      w, sg, mu, E, mask, sw, ssg, smu, sE, smask, iw, ib, PA, PW, SA, SW);
  ltc_dense<<<BB / 2, 1024, 0, stream>>>(
      x, state, gl, rp, cap, ow, ob, PA, PW, SA, SW, fout);
}

// Round 10
// 68.472 us; speedup vs baseline: 8.5878x; 8.4867x over previous
//
#include <hip/hip_runtime.h>
#include <hip/hip_fp16.h>

#define BB 512
#define NN 256
#define SS 128
#define MM 64
#define UNFOLDS 6

static constexpr float EPS_ = 1e-8f;
static constexpr float L2E = 1.4426950408889634f;

// Packed param layout (R6, known-good): float4 per pair of i-entries:
//   {bitcast(half2{a_i, c_i}), wE_i, bitcast(half2{a_i1, c_i1}), wE_i1}
// gate = 1/(1+exp2(a*v + c)); a = -sigma*log2e; c = sigma*mu*log2e
__global__ __launch_bounds__(256) void prep_pack(
    const float* __restrict__ w, const float* __restrict__ sg,
    const float* __restrict__ mu, const float* __restrict__ E,
    const float* __restrict__ mask,
    const float* __restrict__ sw, const float* __restrict__ ssg,
    const float* __restrict__ smu, const float* __restrict__ sE,
    const float* __restrict__ smask,
    const float* __restrict__ iw, const float* __restrict__ ib,
    float4* __restrict__ PQ, float4* __restrict__ SQ) {
  int idx = blockIdx.x * 256 + threadIdx.x;
  union { __half2 h; float f; } u_;
  if (idx < NN * NN) {
    int i = idx >> 8, j = idx & 255;
    float a = sg[idx] * L2E;
    u_.h = __floats2half2_rn(-a, a * mu[idx]);
    float wE = w[idx] * mask[idx] * E[idx];
    float* dst = (float*)(PQ + (i >> 1) * NN + j);
    dst[(i & 1) * 2 + 0] = u_.f;
    dst[(i & 1) * 2 + 1] = wE;
  } else {
    int e = idx - NN * NN;        // < SS*NN
    int s = e >> 8, j = e & 255;
    float a = ssg[e] * L2E;
    // fold input affine: a' = -a*iw[s], c' = a*(smu - ib[s])
    u_.h = __floats2half2_rn(-a * iw[s], a * (smu[e] - ib[s]));
    float wE = sw[e] * smask[e] * sE[e];
    float* dst = (float*)(SQ + (s >> 1) * NN + j);
    dst[(s & 1) * 2 + 0] = u_.f;
    dst[(s & 1) * 2 + 1] = wE;
  }
}

// 4 gates (2 param entries x 2 batches) from one float4 param + one float4 of v
#define GATE4(pq, vv) do { \
  union { float f; __half2 h; } _u0, _u1; \
  _u0.f = (pq).x; _u1.f = (pq).z; \
  float2 ac0 = __half22float2(_u0.h); \
  float2 ac1 = __half22float2(_u1.h); \
  float g0a = __builtin_amdgcn_rcpf(1.f + __builtin_amdgcn_exp2f(fmaf(ac0.x, (vv).x, ac0.y))); \
  float g0b = __builtin_amdgcn_rcpf(1.f + __builtin_amdgcn_exp2f(fmaf(ac0.x, (vv).y, ac0.y))); \
  float g1a = __builtin_amdgcn_rcpf(1.f + __builtin_amdgcn_exp2f(fmaf(ac1.x, (vv).z, ac1.y))); \
  float g1b = __builtin_amdgcn_rcpf(1.f + __builtin_amdgcn_exp2f(fmaf(ac1.x, (vv).w, ac1.y))); \
  n0 = fmaf((pq).y, g0a, n0); d0 = fmaf(__builtin_fabsf((pq).y), g0a, d0); \
  n1 = fmaf((pq).y, g0b, n1); d1 = fmaf(__builtin_fabsf((pq).y), g0b, d1); \
  n0 = fmaf((pq).w, g1a, n0); d0 = fmaf(__builtin_fabsf((pq).w), g1a, d0); \
  n1 = fmaf((pq).w, g1b, n1); d1 = fmaf(__builtin_fabsf((pq).w), g1b, d1); \
} while (0)

// async global->LDS, 16 B per lane, dest = ldsbase + lane*16 (wave-uniform base)
__device__ __forceinline__ void gll16(const float4* g, float4* l) {
  __builtin_amdgcn_global_load_lds(
      (const __attribute__((address_space(1))) void*)g,
      (__attribute__((address_space(3))) void*)l, 16, 0, 0);
}

// one block = 2 batches x all 256 columns, all unfolds; no cross-block deps.
// 1024 threads: j = tid&255 (column), split = tid>>8 (4-way over i).
// Param stream staged via wave-private LDS double buffer (global_load_lds):
// prefetch depth lives in LDS, not VGPRs (R7-R9 spill lesson).
__global__ __launch_bounds__(1024, 4) void ltc_dense(
    const float* __restrict__ x, const float* __restrict__ state,
    const float* __restrict__ gl, const float* __restrict__ rp,
    const float* __restrict__ cap,
    const float* __restrict__ ow, const float* __restrict__ ob,
    const float4* __restrict__ PQ, const float4* __restrict__ SQ,
    float* __restrict__ out) {
  extern __shared__ float4 lds4[];
  float4* stage = lds4;            // [16 waves][2 slots][4 chunks][64 lanes] = 8192
  float4* vA  = stage + 16 * 2 * 4 * 64;  // 128: v[i-pair]{b0,b1,b0,b1}
  float4* vB  = vA + 128;                 // 128
  float4* xt  = vB + 128;                 // 64
  float4* snd = xt + 64;                  // 256: {n0,n1,d0,d1} per column
  float4* red = snd + 256;                // 3*256 partials

  int tid = threadIdx.x;
  int j = tid & 255;
  int split = tid >> 8;
  int wv = tid >> 6;            // wave id 0..15
  int lane = tid & 63;
  int jbase = (wv & 3) * 64;    // wave's column base (j = jbase + lane)
  int bbase = blockIdx.x * 2;
  float4* sbuf = stage + wv * (2 * 4 * 64);   // wave-private staging

  if (tid < 512) {
    int b = tid >> 8, i = tid & 255;
    ((float*)vA)[(i >> 1) * 4 + (i & 1) * 2 + b] = state[(bbase + b) * NN + i];
  } else if (tid < 768) {
    int t = tid - 512, b = t >> 7, s = t & 127;
    ((float*)xt)[(s >> 1) * 4 + (s & 1) * 2 + b] = x[(bbase + b) * SS + s];
  }
  __syncthreads();

  // ---- sensory aggregation (direct loads, one-time) ----
  {
    float n0 = 0, n1 = 0, d0 = 0, d1 = 0;
    const float4* Sp = SQ + split * 16 * NN + j;
    const float4* xq = xt + split * 16;
#pragma unroll
    for (int c = 0; c < 16; ++c) { float4 pq = Sp[c * NN]; float4 vv = xq[c]; GATE4(pq, vv); }
    if (split) red[(split - 1) * 256 + j] = make_float4(n0, n1, d0, d1);
    __syncthreads();
    if (split == 0) {
      float4 r0 = red[j], r1 = red[256 + j], r2 = red[512 + j];
      snd[j] = make_float4(n0 + r0.x + r1.x + r2.x, n1 + r0.y + r1.y + r2.y,
                           d0 + r0.z + r1.z + r2.z, d1 + r0.w + r1.w + r2.w);
    }
    __syncthreads();
  }

  float cmt = cap[j] * (float)UNFOLDS;
  float glv = gl[j];
  float base_ = glv * rp[j];

  // ---- 6 unfolds, v ping-pongs in LDS; params DMA-staged per wave ----
  for (int u = 0; u < UNFOLDS; ++u) {
    const float4* vcur = (u & 1) ? vB : vA;
    float4* vnext = (u & 1) ? vA : vB;
    float n0 = 0, n1 = 0, d0 = 0, d1 = 0;
    // wave's param rows: (split*32 + cc), columns jbase+lane
    const float4* Pb = PQ + (size_t)(split * 32) * NN + jbase + lane;
    const float4* vq = vcur + split * 32;
    // prologue: stage groups 0 and 1 (4 chunks each)
#pragma unroll
    for (int c = 0; c < 4; ++c) gll16(Pb + c * NN, sbuf + c * 64);
#pragma unroll
    for (int c = 0; c < 4; ++c) gll16(Pb + (4 + c) * NN, sbuf + 256 + c * 64);
#pragma unroll
    for (int g = 0; g < 8; ++g) {
      if (g < 7) asm volatile("s_waitcnt vmcnt(4)" ::: "memory");
      else       asm volatile("s_waitcnt vmcnt(0)" ::: "memory");
      const float4* ps = sbuf + (g & 1) * 256;
#pragma unroll
      for (int c = 0; c < 4; ++c) {
        float4 pq = ps[c * 64 + lane];
        float4 vv = vq[g * 4 + c];
        GATE4(pq, vv);
      }
      if (g < 6) {
#pragma unroll
        for (int c = 0; c < 4; ++c)
          gll16(Pb + ((g + 2) * 4 + c) * NN, sbuf + (g & 1) * 256 + c * 64);
      }
    }
    if (split) red[(split - 1) * 256 + j] = make_float4(n0, n1, d0, d1);
    __syncthreads();
    if (split == 0) {
      float4 r0 = red[j], r1 = red[256 + j], r2 = red[512 + j], sj = snd[j];
      float N0 = n0 + r0.x + r1.x + r2.x + sj.x;
      float N1 = n1 + r0.y + r1.y + r2.y + sj.y;
      float D0 = d0 + r0.z + r1.z + r2.z + sj.z;
      float D1 = d1 + r0.w + r1.w + r2.w + sj.w;
      const float* vcf = (const float*)vcur;
      float vj0 = vcf[(j >> 1) * 4 + (j & 1) * 2 + 0];
      float vj1 = vcf[(j >> 1) * 4 + (j & 1) * 2 + 1];
      float va  = (fmaf(cmt, vj0, base_) + N0) * __builtin_amdgcn_rcpf(cmt + glv + D0 + EPS_);
      float vb2 = (fmaf(cmt, vj1, base_) + N1) * __builtin_amdgcn_rcpf(cmt + glv + D1 + EPS_);
      float* vnf = (float*)vnext;
      vnf[(j >> 1) * 4 + (j & 1) * 2 + 0] = va;
      vnf[(j >> 1) * 4 + (j & 1) * 2 + 1] = vb2;
      if (u == UNFOLDS - 1) {
        out[BB * MM + (bbase + 0) * NN + j] = va;
        out[BB * MM + (bbase + 1) * NN + j] = vb2;
        if (j < MM) {
          out[(bbase + 0) * MM + j] = fmaf(va, ow[j], ob[j]);
          out[(bbase + 1) * MM + j] = fmaf(vb2, ow[j], ob[j]);
        }
      }
    }
    __syncthreads();
  }
}

extern "C" void kernel_launch(void* const* d_in, const int* in_sizes, int n_in,
                              void* d_out, int out_size, void* d_ws, size_t ws_size,
                              hipStream_t stream) {
  const float* x     = (const float*)d_in[0];
  const float* state = (const float*)d_in[1];
  const float* gl    = (const float*)d_in[2];
  const float* rp    = (const float*)d_in[3];
  const float* cap   = (const float*)d_in[4];
  const float* w     = (const float*)d_in[5];
  const float* sg    = (const float*)d_in[6];
  const float* mu    = (const float*)d_in[7];
  const float* E     = (const float*)d_in[8];
  const float* sw    = (const float*)d_in[9];
  const float* ssg   = (const float*)d_in[10];
  const float* smu   = (const float*)d_in[11];
  const float* sE    = (const float*)d_in[12];
  const float* mask  = (const float*)d_in[13];
  const float* smask = (const float*)d_in[14];
  const float* iw    = (const float*)d_in[15];
  const float* ib    = (const float*)d_in[16];
  const float* ow    = (const float*)d_in[17];
  const float* ob    = (const float*)d_in[18];

  float4* PQ = (float4*)d_ws;                  // [NN/2][NN] = 512 KiB
  float4* SQ = PQ + (NN / 2) * NN;             // [SS/2][NN] = 256 KiB
  float* fout = (float*)d_out;                 // [B*M out][B*N v]

  // LDS: stage 8192 + vA 128 + vB 128 + xt 64 + snd 256 + red 768 = 9536 float4
  const int smem = 9536 * 16;                  // 152576 B <= 160 KiB
  hipFuncSetAttribute((const void*)ltc_dense,
                      hipFuncAttributeMaxDynamicSharedMemorySize, smem);

  prep_pack<<<(NN * NN + SS * NN) / 256, 256, 0, stream>>>(
      w, sg, mu, E, mask, sw, ssg, smu, sE, smask, iw, ib, PQ, SQ);
  ltc_dense<<<BB / 2, 1024, smem, stream>>>(
      x, state, gl, rp, cap, ow, ob, PQ, SQ, fout);
}